// Round 4
// baseline (896.501 us; speedup 1.0000x reference)
//
#include <hip/hip_runtime.h>
#include <math.h>

#define NN 8192
#define DD 128
#define THRESH 0.15f
#define CBLK 256      // compute blocks (32 rows each)
#define FBLK 768      // fill blocks
#define PHASES 128    // per wave: 4096 cands / 32 per phase

typedef __attribute__((ext_vector_type(8))) short short8;
typedef __attribute__((ext_vector_type(4))) float f32x4;
typedef __attribute__((address_space(1))) const void g_void;
typedef __attribute__((address_space(3))) void l_void;

__device__ __forceinline__ unsigned short f2bf(float f) {
    unsigned int u = __float_as_uint(f);
    return (unsigned short)((u + 0x7fffu + ((u >> 16) & 1u)) >> 16);
}

// insert (v,j) into sorted-desc top-8 (tie: smaller index first)
__device__ __forceinline__ void ins8(float v, int j, float* tv, int* ti) {
    bool in = (v > tv[7]) | ((v == tv[7]) & (j < ti[7]));
    if (!in) return;
#pragma unroll
    for (int s = 7; s >= 1; --s) {
        bool up = (v > tv[s - 1]) | ((v == tv[s - 1]) & (j < ti[s - 1]));
        tv[s] = up ? tv[s - 1] : v;
        ti[s] = up ? ti[s - 1] : j;
        if (!up) return;
    }
    tv[0] = v; ti[0] = j;
}

__device__ __forceinline__ void gl2lds16(const void* g, void* l) {
    __builtin_amdgcn_global_load_lds((g_void*)g, (l_void*)l, 16, 0, 0);
}

// ------- K1: normalize rows, emit bf16 x-hat (row-major, 256B/row) -------
__global__ __launch_bounds__(256) void norm_rows(const float* __restrict__ x,
                                                 unsigned int* __restrict__ xb) {
    const int t = threadIdx.x;
    const int lane = t & 63;
    const int i = blockIdx.x * 4 + (t >> 6);
    float2 v = reinterpret_cast<const float2*>(x + (size_t)i * DD)[lane];
    float ss = v.x * v.x + v.y * v.y;
#pragma unroll
    for (int d = 1; d < 64; d <<= 1) ss += __shfl_xor(ss, d);
    float inv = 1.0f / fmaxf(sqrtf(ss), 1e-12f);
    xb[(size_t)i * 64 + lane] = ((unsigned int)f2bf(v.y * inv) << 16) | f2bf(v.x * inv);
}

// ------- K2: role-split. 1 of 4 blocks: MFMA sweep w/ LDS-staged coalesced
// candidates (swizzled, wave-private dbuf, counted vmcnt). 3 of 4: zero-fill. ----
__global__ __launch_bounds__(256, 2) void build_fused(const unsigned int* __restrict__ xbw,
                                                      int* __restrict__ cidx,
                                                      float* __restrict__ out) {
    const int t = threadIdx.x;
    const int bid = blockIdx.x;

    if (bid & 3) {
        // ---- fill role: grid-stride plain float4 stores over both outputs ----
        const int fid = (bid >> 2) * 3 + (bid & 3) - 1;       // 0..767
        f32x4* o = reinterpret_cast<f32x4*>(out);
        const f32x4 z = {0.f, 0.f, 0.f, 0.f};
        const size_t total = (size_t)NN * NN / 2;             // f32x4 count, both arrays
        for (size_t idx = (size_t)fid * 256 + t; idx < total; idx += (size_t)FBLK * 256)
            o[idx] = z;
        return;
    }

    // ---- compute role ----
    __shared__ char lds[4][16384];        // per-wave double buffer (2 x 8KB)
    __shared__ float smv[2][16][2][8];
    __shared__ int   smi[2][16][2][8];

    const int cb   = bid >> 2;            // 0..255, rows cb*32..+31
    const int lane = t & 63;
    const int w    = t >> 6;
    const int rg   = w >> 1;              // row-group 0/1 (16 rows each)
    const int hs   = w & 1;               // half-strip of candidates
    const int i0   = cb * 32 + rg * 16;
    const int l15  = lane & 15;
    const int r    = lane >> 4;           // 0..3
    const int i    = i0 + l15;            // this lane's output row (D-col)
    const short* xbs = reinterpret_cast<const short*>(xbw);

    // B-frags: lane holds xhat[i][kc*32 + r*8 .. +7] (one-time strided gather)
    short8 rf[4];
#pragma unroll
    for (int kc = 0; kc < 4; ++kc)
        rf[kc] = *reinterpret_cast<const short8*>(xbs + (size_t)i * DD + kc * 32 + r * 8);

    // producer: per-lane pre-swizzled global offset (k even); k odd = ^0x40
    const int voffE_g = r * 256 + ((l15 ^ r) << 4);
    // consumer: per-lane swizzled ds base (kc even); kc odd = ^0x40
    const unsigned dsE0 = (unsigned)(w * 16384 + l15 * 256 + ((r ^ (lane & 7)) << 4));
    const char* gstrip = reinterpret_cast<const char*>(xbs) + (size_t)hs * 4096 * 256;
    char* Lb = &lds[0][0];

    float tv[8]; int ti[8];
#pragma unroll
    for (int s = 0; s < 8; ++s) { tv[s] = -1e30f; ti[s] = 0x7fffffff; }

    asm volatile("s_waitcnt vmcnt(0)" ::: "memory");   // drain rf loads: clean baseline

    // stage phase 0 into buf 0
#pragma unroll
    for (int k = 0; k < 8; ++k)
        gl2lds16(gstrip + k * 1024 + (voffE_g ^ ((k & 1) << 6)),
                 Lb + w * 16384 + k * 1024);

    for (int p = 0; p < PHASES; ++p) {
        const int buf = p & 1;
        if (p + 1 < PHASES) {
            const char* pb = gstrip + (size_t)(p + 1) * 8192;
            char* lb = Lb + w * 16384 + (buf ^ 1) * 8192;
#pragma unroll
            for (int k = 0; k < 8; ++k)
                gl2lds16(pb + k * 1024 + (voffE_g ^ ((k & 1) << 6)), lb + k * 1024);
            asm volatile("s_waitcnt vmcnt(8)" ::: "memory");   // current buf ready
        } else {
            asm volatile("s_waitcnt vmcnt(0)" ::: "memory");
        }
        const unsigned dE = dsE0 + buf * 8192;
#pragma unroll
        for (int cc = 0; cc < 2; ++cc) {
            f32x4 acc = {0.f, 0.f, 0.f, 0.f};
#pragma unroll
            for (int kc = 0; kc < 4; ++kc) {
                unsigned off = (dE ^ ((kc & 1) << 6)) + cc * 4096 + (kc >> 1) * 128;
                short8 a = *reinterpret_cast<const short8*>(Lb + off);
                acc = __builtin_amdgcn_mfma_f32_16x16x32_bf16(a, rf[kc], acc, 0, 0, 0);
            }
            const int jb = hs * 4096 + p * 32 + cc * 16 + r * 4;
            float m = fmaxf(fmaxf(acc[0], acc[1]), fmaxf(acc[2], acc[3]));
            if (m >= tv[7]) {            // cheap reject: none of the 4 can enter
#pragma unroll
                for (int q = 0; q < 4; ++q) {
                    int j = jb + q;
                    if (j != i) ins8(acc[q], j, tv, ti);
                }
            }
        }
    }

    // merge the 4 lane-groups sharing row i (same l15, different r)
#pragma unroll
    for (int d = 16; d < 64; d <<= 1) {
        float ov[8]; int oi[8];
#pragma unroll
        for (int s = 0; s < 8; ++s) { ov[s] = __shfl_xor(tv[s], d); oi[s] = __shfl_xor(ti[s], d); }
#pragma unroll
        for (int s = 0; s < 8; ++s) ins8(ov[s], oi[s], tv, ti);
    }
    if (lane < 16) {
#pragma unroll
        for (int s = 0; s < 8; ++s) { smv[rg][l15][hs][s] = tv[s]; smi[rg][l15][hs][s] = ti[s]; }
    }
    __syncthreads();
    if (t < 32) {
        const int g = t >> 4, rl = t & 15;
        float mv[8]; int mi[8];
#pragma unroll
        for (int s = 0; s < 8; ++s) { mv[s] = smv[g][rl][0][s]; mi[s] = smi[g][rl][0][s]; }
#pragma unroll
        for (int s = 0; s < 8; ++s) ins8(smv[g][rl][1][s], smi[g][rl][1][s], mv, mi);
        const int row = cb * 32 + g * 16 + rl;
#pragma unroll
        for (int s = 0; s < 8; ++s) cidx[(size_t)row * 8 + s] = mi[s];
    }
}

// ------- K3: exact fp32 re-rank of 8 candidates, scatter adj/ew -------
__global__ __launch_bounds__(256) void rerank(const float* __restrict__ x,
                                              const int* __restrict__ cidx,
                                              float* __restrict__ adj,
                                              float* __restrict__ ew) {
    const int t = threadIdx.x;
    const int lane = t & 63;
    const int i = blockIdx.x * 4 + (t >> 6);
    float2 a = reinterpret_cast<const float2*>(x + (size_t)i * DD)[lane];
    float ss = a.x * a.x + a.y * a.y;
#pragma unroll
    for (int d = 1; d < 64; d <<= 1) ss += __shfl_xor(ss, d);
    float ni = fmaxf(sqrtf(ss), 1e-12f);

    int myc = (lane < 8) ? cidx[(size_t)i * 8 + lane] : 0;
    float sv[8]; int jv[8];
#pragma unroll
    for (int c = 0; c < 8; ++c) {
        int j = __shfl(myc, c);
        float2 b = reinterpret_cast<const float2*>(x + (size_t)j * DD)[lane];
        float dp = a.x * b.x + a.y * b.y;
        float sb = b.x * b.x + b.y * b.y;
#pragma unroll
        for (int d = 1; d < 64; d <<= 1) { dp += __shfl_xor(dp, d); sb += __shfl_xor(sb, d); }
        float nj = fmaxf(sqrtf(sb), 1e-12f);
        sv[c] = dp / (ni * nj);
        jv[c] = j;
    }
    if (lane == 0) {
#pragma unroll
        for (int c = 0; c < 8; ++c) {
            int beats = 0;
#pragma unroll
            for (int c2 = 0; c2 < 8; ++c2)
                beats += ((sv[c2] > sv[c]) | ((sv[c2] == sv[c]) & (jv[c2] < jv[c]))) ? 1 : 0;
            if (beats < 4 && sv[c] > THRESH) {
                adj[(size_t)i * NN + jv[c]] = 1.0f;
                ew [(size_t)i * NN + jv[c]] = sv[c];
            }
        }
    }
}

extern "C" void kernel_launch(void* const* d_in, const int* in_sizes, int n_in,
                              void* d_out, int out_size, void* d_ws, size_t ws_size,
                              hipStream_t stream) {
    const float* x = (const float*)d_in[0];
    unsigned int* xb = (unsigned int*)d_ws;                 // 2 MB bf16 x-hat
    int* cidx = (int*)((char*)d_ws + (2u << 20));           // 256 KB candidate indices
    float* adj = (float*)d_out;
    float* ew  = adj + (size_t)NN * NN;
    hipLaunchKernelGGL(norm_rows,   dim3(NN / 4), dim3(256), 0, stream, x, xb);
    hipLaunchKernelGGL(build_fused, dim3(1024),   dim3(256), 0, stream, xb, cidx, adj);
    hipLaunchKernelGGL(rerank,      dim3(NN / 4), dim3(256), 0, stream, x, cidx, adj, ew);
}

// Round 6
// 492.163 us; speedup vs baseline: 1.8216x; 1.8216x over previous
//
#include <hip/hip_runtime.h>
#include <math.h>

#define NN 8192
#define DD 128
#define THRESH 0.15f
#define NG (NN / 16)          // 512 candidate groups of 16

typedef __attribute__((ext_vector_type(8))) short short8;
typedef __attribute__((ext_vector_type(4))) float f32x4;
typedef __attribute__((ext_vector_type(4))) unsigned int u32x4;

__device__ __forceinline__ unsigned short f2bf(float f) {
    unsigned int u = __float_as_uint(f);
    return (unsigned short)((u + 0x7fffu + ((u >> 16) & 1u)) >> 16);
}

// insert (v,j) into sorted-desc top-8 (tie: smaller index first)
__device__ __forceinline__ void ins8(float v, int j, float* tv, int* ti) {
    bool in = (v > tv[7]) | ((v == tv[7]) & (j < ti[7]));
    if (!in) return;
#pragma unroll
    for (int s = 7; s >= 1; --s) {
        bool up = (v > tv[s - 1]) | ((v == tv[s - 1]) & (j < ti[s - 1]));
        tv[s] = up ? tv[s - 1] : v;
        ti[s] = up ? ti[s - 1] : j;
        if (!up) return;
    }
    tv[0] = v; ti[0] = j;
}

// ---- K1: normalize rows, emit bf16 x-hat in MFMA-fragment-major layout ----
// F[(g*4+kc)*64 + r*16 + row] (16B) = xhat[g*16+row][kc*32 + r*8 .. +7]
__global__ __launch_bounds__(256) void norm_frag(const float* __restrict__ x,
                                                 u32x4* __restrict__ F) {
    const int t = threadIdx.x;
    const int c = blockIdx.x;            // candidate group
    const int row = t >> 4;              // 0..15 (16 consecutive lanes per row)
    const int seg = t & 15;              // k-octet
    const float* xr = x + (size_t)(c * 16 + row) * DD + seg * 8;
    float4 v0 = reinterpret_cast<const float4*>(xr)[0];
    float4 v1 = reinterpret_cast<const float4*>(xr)[1];
    float ss = v0.x*v0.x + v0.y*v0.y + v0.z*v0.z + v0.w*v0.w
             + v1.x*v1.x + v1.y*v1.y + v1.z*v1.z + v1.w*v1.w;
#pragma unroll
    for (int d = 1; d < 16; d <<= 1) ss += __shfl_xor(ss, d);
    const float inv = 1.0f / fmaxf(sqrtf(ss), 1e-12f);
    u32x4 p;
    p.x = ((unsigned)f2bf(v0.y*inv) << 16) | f2bf(v0.x*inv);
    p.y = ((unsigned)f2bf(v0.w*inv) << 16) | f2bf(v0.z*inv);
    p.z = ((unsigned)f2bf(v1.y*inv) << 16) | f2bf(v1.x*inv);
    p.w = ((unsigned)f2bf(v1.w*inv) << 16) | f2bf(v1.z*inv);
    const int kc = seg >> 2, r = seg & 3;
    F[(size_t)(c * 4 + kc) * 64 + r * 16 + row] = p;
}

// ---- K2: pure-compute MFMA sweep, coalesced fragment loads, per-row top-8 ----
__global__ __launch_bounds__(512) void build_topk(const short8* __restrict__ F,
                                                  int* __restrict__ cidx) {
    __shared__ float smv[32][8][8];
    __shared__ int   smi[32][8][8];
    const int t = threadIdx.x, lane = t & 63, w = t >> 6;   // 8 waves
    const int i0 = blockIdx.x * 32;
    const int l15 = lane & 15, r = lane >> 4;
    const int g0 = i0 >> 4;

    short8 rf0[4], rf1[4];          // B-frags for the block's two 16-row groups
#pragma unroll
    for (int kc = 0; kc < 4; ++kc) {
        rf0[kc] = F[(size_t)(g0 * 4 + kc) * 64 + lane];
        rf1[kc] = F[(size_t)((g0 + 1) * 4 + kc) * 64 + lane];
    }

    float tv0[8], tv1[8]; int ti0[8], ti1[8];
#pragma unroll
    for (int s = 0; s < 8; ++s) {
        tv0[s] = -1e30f; ti0[s] = 0x7fffffff;
        tv1[s] = -1e30f; ti1[s] = 0x7fffffff;
    }
    const int ia = i0 + l15, ib = i0 + 16 + l15;

    for (int cg = w; cg < NG; cg += 8) {       // 64 groups per wave
        const short8 a0 = F[(size_t)(cg * 4 + 0) * 64 + lane];
        const short8 a1 = F[(size_t)(cg * 4 + 1) * 64 + lane];
        const short8 a2 = F[(size_t)(cg * 4 + 2) * 64 + lane];
        const short8 a3 = F[(size_t)(cg * 4 + 3) * 64 + lane];
        f32x4 acc0 = {0.f, 0.f, 0.f, 0.f}, acc1 = {0.f, 0.f, 0.f, 0.f};
        acc0 = __builtin_amdgcn_mfma_f32_16x16x32_bf16(a0, rf0[0], acc0, 0, 0, 0);
        acc1 = __builtin_amdgcn_mfma_f32_16x16x32_bf16(a0, rf1[0], acc1, 0, 0, 0);
        acc0 = __builtin_amdgcn_mfma_f32_16x16x32_bf16(a1, rf0[1], acc0, 0, 0, 0);
        acc1 = __builtin_amdgcn_mfma_f32_16x16x32_bf16(a1, rf1[1], acc1, 0, 0, 0);
        acc0 = __builtin_amdgcn_mfma_f32_16x16x32_bf16(a2, rf0[2], acc0, 0, 0, 0);
        acc1 = __builtin_amdgcn_mfma_f32_16x16x32_bf16(a2, rf1[2], acc1, 0, 0, 0);
        acc0 = __builtin_amdgcn_mfma_f32_16x16x32_bf16(a3, rf0[3], acc0, 0, 0, 0);
        acc1 = __builtin_amdgcn_mfma_f32_16x16x32_bf16(a3, rf1[3], acc1, 0, 0, 0);

        const int jb = cg * 16 + r * 4;
        float m0 = fmaxf(fmaxf(acc0[0], acc0[1]), fmaxf(acc0[2], acc0[3]));
        if (m0 >= tv0[7]) {
#pragma unroll
            for (int q = 0; q < 4; ++q) {
                int j = jb + q;
                if (j != ia) ins8(acc0[q], j, tv0, ti0);
            }
        }
        float m1 = fmaxf(fmaxf(acc1[0], acc1[1]), fmaxf(acc1[2], acc1[3]));
        if (m1 >= tv1[7]) {
#pragma unroll
            for (int q = 0; q < 4; ++q) {
                int j = jb + q;
                if (j != ib) ins8(acc1[q], j, tv1, ti1);
            }
        }
    }

    // merge the 4 r-groups sharing each row (lanes l, l+16, l+32, l+48)
#pragma unroll
    for (int d = 16; d < 64; d <<= 1) {
        float ov[8]; int oi[8];
#pragma unroll
        for (int s = 0; s < 8; ++s) { ov[s] = __shfl_xor(tv0[s], d); oi[s] = __shfl_xor(ti0[s], d); }
#pragma unroll
        for (int s = 0; s < 8; ++s) ins8(ov[s], oi[s], tv0, ti0);
#pragma unroll
        for (int s = 0; s < 8; ++s) { ov[s] = __shfl_xor(tv1[s], d); oi[s] = __shfl_xor(ti1[s], d); }
#pragma unroll
        for (int s = 0; s < 8; ++s) ins8(ov[s], oi[s], tv1, ti1);
    }
    if (lane < 16) {
#pragma unroll
        for (int s = 0; s < 8; ++s) {
            smv[l15][w][s] = tv0[s];      smi[l15][w][s] = ti0[s];
            smv[16 + l15][w][s] = tv1[s]; smi[16 + l15][w][s] = ti1[s];
        }
    }
    __syncthreads();
    if (t < 32) {
        float mv[8]; int mi[8];
#pragma unroll
        for (int s = 0; s < 8; ++s) { mv[s] = smv[t][0][s]; mi[s] = smi[t][0][s]; }
#pragma unroll
        for (int ww = 1; ww < 8; ++ww)
#pragma unroll
            for (int s = 0; s < 8; ++s) ins8(smv[t][ww][s], smi[t][ww][s], mv, mi);
#pragma unroll
        for (int s = 0; s < 8; ++s) cidx[(size_t)(i0 + t) * 8 + s] = mi[s];
    }
}

// ---- K-fill: plain cached grid-stride zero of both outputs (fillBuffer pattern) ----
__global__ __launch_bounds__(256) void fill_zero(f32x4* __restrict__ o) {
    const f32x4 z = {0.f, 0.f, 0.f, 0.f};
    const size_t total = (size_t)NN * NN / 2;        // f32x4 over both arrays
    const size_t stride = (size_t)2048 * 256;
    size_t idx = (size_t)blockIdx.x * 256 + threadIdx.x;
#pragma unroll 4
    for (; idx < total; idx += stride) o[idx] = z;
}

// ---- K3: exact fp32 re-rank of 8 candidates, scatter adj/ew ----
__global__ __launch_bounds__(256) void rerank(const float* __restrict__ x,
                                              const int* __restrict__ cidx,
                                              float* __restrict__ adj,
                                              float* __restrict__ ew) {
    const int t = threadIdx.x;
    const int lane = t & 63;
    const int i = blockIdx.x * 4 + (t >> 6);
    float2 a = reinterpret_cast<const float2*>(x + (size_t)i * DD)[lane];
    float ss = a.x * a.x + a.y * a.y;
#pragma unroll
    for (int d = 1; d < 64; d <<= 1) ss += __shfl_xor(ss, d);
    float ni = fmaxf(sqrtf(ss), 1e-12f);

    int myc = (lane < 8) ? cidx[(size_t)i * 8 + lane] : 0;
    float sv[8]; int jv[8];
#pragma unroll
    for (int c = 0; c < 8; ++c) {
        int j = __shfl(myc, c);
        float2 b = reinterpret_cast<const float2*>(x + (size_t)j * DD)[lane];
        float dp = a.x * b.x + a.y * b.y;
        float sb = b.x * b.x + b.y * b.y;
#pragma unroll
        for (int d = 1; d < 64; d <<= 1) { dp += __shfl_xor(dp, d); sb += __shfl_xor(sb, d); }
        float nj = fmaxf(sqrtf(sb), 1e-12f);
        sv[c] = dp / (ni * nj);
        jv[c] = j;
    }
    if (lane == 0) {
#pragma unroll
        for (int c = 0; c < 8; ++c) {
            int beats = 0;
#pragma unroll
            for (int c2 = 0; c2 < 8; ++c2)
                beats += ((sv[c2] > sv[c]) | ((sv[c2] == sv[c]) & (jv[c2] < jv[c]))) ? 1 : 0;
            if (beats < 4 && sv[c] > THRESH) {
                adj[(size_t)i * NN + jv[c]] = 1.0f;
                ew [(size_t)i * NN + jv[c]] = sv[c];
            }
        }
    }
}

extern "C" void kernel_launch(void* const* d_in, const int* in_sizes, int n_in,
                              void* d_out, int out_size, void* d_ws, size_t ws_size,
                              hipStream_t stream) {
    const float* x = (const float*)d_in[0];
    u32x4* F = (u32x4*)d_ws;                               // 2 MB fragment-major x-hat
    int* cidx = (int*)((char*)d_ws + (2u << 20));          // 256 KB candidate indices
    float* adj = (float*)d_out;
    float* ew  = adj + (size_t)NN * NN;

    hipLaunchKernelGGL(norm_frag,  dim3(NG),     dim3(256), 0, stream, x, F);
    hipLaunchKernelGGL(build_topk, dim3(NN/32),  dim3(512), 0, stream,
                       (const short8*)F, cidx);
    hipLaunchKernelGGL(fill_zero,  dim3(2048),   dim3(256), 0, stream, (f32x4*)d_out);
    hipLaunchKernelGGL(rerank,     dim3(NN/4),   dim3(256), 0, stream, x, cidx, adj, ew);
}

// Round 7
// 275.204 us; speedup vs baseline: 3.2576x; 1.7884x over previous
//
#include <hip/hip_runtime.h>
#include <math.h>

#define NN 8192
#define DD 128
#define THRESH 0.15f
#define NG (NN / 16)          // 512 candidate groups of 16
#define T0 0.147f             // absolute prefilter (bf16-safe: 0.15 - 10sigma)
#define BWID 0.025f           // histogram bucket width
#define DELTA 0.004f          // 2x bf16 score error bound
#define CAP 96                // per-row candidate list capacity

typedef __attribute__((ext_vector_type(8))) short short8;
typedef __attribute__((ext_vector_type(4))) float f32x4;
typedef __attribute__((ext_vector_type(4))) unsigned int u32x4;

__device__ __forceinline__ unsigned short f2bf(float f) {
    unsigned int u = __float_as_uint(f);
    return (unsigned short)((u + 0x7fffu + ((u >> 16) & 1u)) >> 16);
}

// sorted-desc top-4 insert (tie: smaller index). Used only on wave-uniform data.
__device__ __forceinline__ void ins4(float v, int j, float* tv, int* ti) {
    bool b3 = (v > tv[3]) | ((v == tv[3]) & (j < ti[3]));
    if (b3) {
        bool b0 = (v > tv[0]) | ((v == tv[0]) & (j < ti[0]));
        bool b1 = (v > tv[1]) | ((v == tv[1]) & (j < ti[1]));
        bool b2 = (v > tv[2]) | ((v == tv[2]) & (j < ti[2]));
        if (b0)      { tv[3]=tv[2];ti[3]=ti[2]; tv[2]=tv[1];ti[2]=ti[1]; tv[1]=tv[0];ti[1]=ti[0]; tv[0]=v;ti[0]=j; }
        else if (b1) { tv[3]=tv[2];ti[3]=ti[2]; tv[2]=tv[1];ti[2]=ti[1]; tv[1]=v;ti[1]=j; }
        else if (b2) { tv[3]=tv[2];ti[3]=ti[2]; tv[2]=v;ti[2]=j; }
        else         { tv[3]=v;ti[3]=j; }
    }
}

// ---- K-fill: plain cached grid-stride zero of both outputs ----
__global__ __launch_bounds__(256) void fill_zero(f32x4* __restrict__ o) {
    const f32x4 z = {0.f, 0.f, 0.f, 0.f};
    const size_t total = (size_t)NN * NN / 2;        // f32x4 over both arrays
    const size_t stride = (size_t)2048 * 256;
    size_t idx = (size_t)blockIdx.x * 256 + threadIdx.x;
#pragma unroll 4
    for (; idx < total; idx += stride) o[idx] = z;
}

// ---- K1: normalize rows, emit bf16 x-hat in MFMA-fragment-major layout ----
// F[(g*4+kc)*64 + r*16 + row] (16B) = xhat[g*16+row][kc*32 + r*8 .. +7]
__global__ __launch_bounds__(256) void norm_frag(const float* __restrict__ x,
                                                 u32x4* __restrict__ F) {
    const int t = threadIdx.x;
    const int c = blockIdx.x;
    const int row = t >> 4;
    const int seg = t & 15;
    const float* xr = x + (size_t)(c * 16 + row) * DD + seg * 8;
    float4 v0 = reinterpret_cast<const float4*>(xr)[0];
    float4 v1 = reinterpret_cast<const float4*>(xr)[1];
    float ss = v0.x*v0.x + v0.y*v0.y + v0.z*v0.z + v0.w*v0.w
             + v1.x*v1.x + v1.y*v1.y + v1.z*v1.z + v1.w*v1.w;
#pragma unroll
    for (int d = 1; d < 16; d <<= 1) ss += __shfl_xor(ss, d);
    const float inv = 1.0f / fmaxf(sqrtf(ss), 1e-12f);
    u32x4 p;
    p.x = ((unsigned)f2bf(v0.y*inv) << 16) | f2bf(v0.x*inv);
    p.y = ((unsigned)f2bf(v0.w*inv) << 16) | f2bf(v0.z*inv);
    p.z = ((unsigned)f2bf(v1.y*inv) << 16) | f2bf(v1.x*inv);
    p.w = ((unsigned)f2bf(v1.w*inv) << 16) | f2bf(v1.z*inv);
    const int kc = seg >> 2, r = seg & 3;
    F[(size_t)(c * 4 + kc) * 64 + r * 16 + row] = p;
}

// ---- K2: two-sweep histogram select + exact fp32 rerank + scatter ----
__global__ __launch_bounds__(512) void build(const short8* __restrict__ F,
                                             const float* __restrict__ x,
                                             float* __restrict__ adj,
                                             float* __restrict__ ew) {
    __shared__ unsigned hist[32][8];
    __shared__ unsigned cnt[32];
    __shared__ float rowthr[32];
    __shared__ float lv[32][CAP];
    __shared__ int   li[32][CAP];

    const int t = threadIdx.x, lane = t & 63, w = t >> 6;   // 8 waves
    const int i0 = blockIdx.x * 32;
    const int l15 = lane & 15, r = lane >> 4;
    const int g0 = i0 >> 4;
    const int ia = i0 + l15, ib = ia + 16;                  // global rows

    if (t < 256) reinterpret_cast<unsigned*>(hist)[t] = 0u;
    if (t >= 256 && t < 288) cnt[t - 256] = 0u;

    short8 rf0[4], rf1[4];          // B-frags for the block's two 16-row groups
#pragma unroll
    for (int kc = 0; kc < 4; ++kc) {
        rf0[kc] = F[(size_t)(g0 * 4 + kc) * 64 + lane];
        rf1[kc] = F[(size_t)((g0 + 1) * 4 + kc) * 64 + lane];
    }
    __syncthreads();

    // ---- sweep 1: per-row 8-bucket histogram of sims above T0 ----
    for (int cg = w; cg < NG; cg += 8) {
        const short8 a0 = F[(size_t)(cg * 4 + 0) * 64 + lane];
        const short8 a1 = F[(size_t)(cg * 4 + 1) * 64 + lane];
        const short8 a2 = F[(size_t)(cg * 4 + 2) * 64 + lane];
        const short8 a3 = F[(size_t)(cg * 4 + 3) * 64 + lane];
        f32x4 acc0 = {0.f, 0.f, 0.f, 0.f}, acc1 = {0.f, 0.f, 0.f, 0.f};
        acc0 = __builtin_amdgcn_mfma_f32_16x16x32_bf16(a0, rf0[0], acc0, 0, 0, 0);
        acc1 = __builtin_amdgcn_mfma_f32_16x16x32_bf16(a0, rf1[0], acc1, 0, 0, 0);
        acc0 = __builtin_amdgcn_mfma_f32_16x16x32_bf16(a1, rf0[1], acc0, 0, 0, 0);
        acc1 = __builtin_amdgcn_mfma_f32_16x16x32_bf16(a1, rf1[1], acc1, 0, 0, 0);
        acc0 = __builtin_amdgcn_mfma_f32_16x16x32_bf16(a2, rf0[2], acc0, 0, 0, 0);
        acc1 = __builtin_amdgcn_mfma_f32_16x16x32_bf16(a2, rf1[2], acc1, 0, 0, 0);
        acc0 = __builtin_amdgcn_mfma_f32_16x16x32_bf16(a3, rf0[3], acc0, 0, 0, 0);
        acc1 = __builtin_amdgcn_mfma_f32_16x16x32_bf16(a3, rf1[3], acc1, 0, 0, 0);
        const int jb = cg * 16 + r * 4;
#pragma unroll
        for (int q = 0; q < 4; ++q) {
            const int j = jb + q;
            float v = acc0[q];
            if (v > T0 && j != ia) {
                int b = (int)((v - T0) * 40.0f); if (b > 7) b = 7;
                atomicAdd(&hist[l15][b], 1u);
            }
            v = acc1[q];
            if (v > T0 && j != ib) {
                int b = (int)((v - T0) * 40.0f); if (b > 7) b = 7;
                atomicAdd(&hist[l15 + 16][b], 1u);
            }
        }
    }
    __syncthreads();

    // ---- per-row threshold: highest bucket with cumulative count >= 8 ----
    if (t < 32) {
        unsigned c = 0; int pick = 0;
#pragma unroll
        for (int b = 7; b >= 0; --b) {
            c += hist[t][b];
            if (c >= 8u) { pick = b; break; }
        }
        rowthr[t] = T0 + BWID * (float)pick - DELTA;
    }
    __syncthreads();
    const float sTa = rowthr[l15], sTb = rowthr[l15 + 16];

    // ---- sweep 2: append candidates above per-row threshold ----
    for (int cg = w; cg < NG; cg += 8) {
        const short8 a0 = F[(size_t)(cg * 4 + 0) * 64 + lane];
        const short8 a1 = F[(size_t)(cg * 4 + 1) * 64 + lane];
        const short8 a2 = F[(size_t)(cg * 4 + 2) * 64 + lane];
        const short8 a3 = F[(size_t)(cg * 4 + 3) * 64 + lane];
        f32x4 acc0 = {0.f, 0.f, 0.f, 0.f}, acc1 = {0.f, 0.f, 0.f, 0.f};
        acc0 = __builtin_amdgcn_mfma_f32_16x16x32_bf16(a0, rf0[0], acc0, 0, 0, 0);
        acc1 = __builtin_amdgcn_mfma_f32_16x16x32_bf16(a0, rf1[0], acc1, 0, 0, 0);
        acc0 = __builtin_amdgcn_mfma_f32_16x16x32_bf16(a1, rf0[1], acc0, 0, 0, 0);
        acc1 = __builtin_amdgcn_mfma_f32_16x16x32_bf16(a1, rf1[1], acc1, 0, 0, 0);
        acc0 = __builtin_amdgcn_mfma_f32_16x16x32_bf16(a2, rf0[2], acc0, 0, 0, 0);
        acc1 = __builtin_amdgcn_mfma_f32_16x16x32_bf16(a2, rf1[2], acc1, 0, 0, 0);
        acc0 = __builtin_amdgcn_mfma_f32_16x16x32_bf16(a3, rf0[3], acc0, 0, 0, 0);
        acc1 = __builtin_amdgcn_mfma_f32_16x16x32_bf16(a3, rf1[3], acc1, 0, 0, 0);
        const int jb = cg * 16 + r * 4;
#pragma unroll
        for (int q = 0; q < 4; ++q) {
            const int j = jb + q;
            float v = acc0[q];
            if (v > sTa && j != ia) {
                unsigned p = atomicAdd(&cnt[l15], 1u);
                if (p < CAP) { lv[l15][p] = v; li[l15][p] = j; }
            }
            v = acc1[q];
            if (v > sTb && j != ib) {
                unsigned p = atomicAdd(&cnt[l15 + 16], 1u);
                if (p < CAP) { lv[l15 + 16][p] = v; li[l15 + 16][p] = j; }
            }
        }
    }
    __syncthreads();

    // ---- exact fp32 rerank + scatter: wave w handles rows w*4 .. w*4+3 ----
    for (int rr = 0; rr < 4; ++rr) {
        const int lrow = w * 4 + rr;
        const int i = i0 + lrow;
        const int n = min((int)cnt[lrow], CAP);
        const float2 a = reinterpret_cast<const float2*>(x + (size_t)i * DD)[lane];
        float ss = a.x * a.x + a.y * a.y;
#pragma unroll
        for (int d = 1; d < 64; d <<= 1) ss += __shfl_xor(ss, d);
        const float ni = fmaxf(sqrtf(ss), 1e-12f);
        float tv[4]; int ti[4];
#pragma unroll
        for (int s = 0; s < 4; ++s) { tv[s] = -1e30f; ti[s] = 0x7fffffff; }
        for (int c = 0; c < n; ++c) {
            const int j = li[lrow][c];
            const float2 b = reinterpret_cast<const float2*>(x + (size_t)j * DD)[lane];
            float dp = a.x * b.x + a.y * b.y;
            float sb = b.x * b.x + b.y * b.y;
#pragma unroll
            for (int d = 1; d < 64; d <<= 1) {
                dp += __shfl_xor(dp, d);
                sb += __shfl_xor(sb, d);
            }
            const float sim = dp / (ni * fmaxf(sqrtf(sb), 1e-12f));
            ins4(sim, j, tv, ti);    // wave-uniform -> cheap uniform branches
        }
        if (lane == 0) {
#pragma unroll
            for (int s = 0; s < 4; ++s)
                if (tv[s] > THRESH) {
                    adj[(size_t)i * NN + ti[s]] = 1.0f;
                    ew [(size_t)i * NN + ti[s]] = tv[s];
                }
        }
    }
}

extern "C" void kernel_launch(void* const* d_in, const int* in_sizes, int n_in,
                              void* d_out, int out_size, void* d_ws, size_t ws_size,
                              hipStream_t stream) {
    const float* x = (const float*)d_in[0];
    u32x4* F = (u32x4*)d_ws;                               // 2 MB fragment-major x-hat
    float* adj = (float*)d_out;
    float* ew  = adj + (size_t)NN * NN;

    hipLaunchKernelGGL(fill_zero, dim3(2048), dim3(256), 0, stream, (f32x4*)d_out);
    hipLaunchKernelGGL(norm_frag, dim3(NG),   dim3(256), 0, stream, x, F);
    hipLaunchKernelGGL(build,     dim3(NN/32), dim3(512), 0, stream,
                       (const short8*)F, x, adj, ew);
}

// Round 8
// 240.025 us; speedup vs baseline: 3.7350x; 1.1466x over previous
//
#include <hip/hip_runtime.h>
#include <math.h>

#define NN 8192
#define DD 128
#define THRESH 0.15f
#define NG (NN / 16)          // 512 candidate groups of 16
#define T0 0.147f             // absolute prefilter (bf16-safe: 0.15 - margin)
#define BWID 0.025f           // histogram bucket width
#define DELTA 0.004f          // 2x bf16 score error bound
#define CAP 96                // per-row candidate list capacity
#define KSEL 5u               // cumulative count incl. self (=4 excl.) -> top-4 safe

typedef __attribute__((ext_vector_type(8))) short short8;
typedef __attribute__((ext_vector_type(4))) float f32x4;
typedef __attribute__((ext_vector_type(4))) unsigned int u32x4;
typedef unsigned long long u64;

__device__ __forceinline__ unsigned short f2bf(float f) {
    unsigned int u = __float_as_uint(f);
    return (unsigned short)((u + 0x7fffu + ((u >> 16) & 1u)) >> 16);
}

__device__ __forceinline__ u64 shfl_xor_u64(u64 v, int d) {
    unsigned lo = (unsigned)v, hi = (unsigned)(v >> 32);
    lo = __shfl_xor(lo, d); hi = __shfl_xor(hi, d);
    return ((u64)hi << 32) | lo;
}

// sorted-desc top-4 insert (tie: smaller index). Only on wave-uniform data.
__device__ __forceinline__ void ins4(float v, int j, float* tv, int* ti) {
    bool b3 = (v > tv[3]) | ((v == tv[3]) & (j < ti[3]));
    if (b3) {
        bool b0 = (v > tv[0]) | ((v == tv[0]) & (j < ti[0]));
        bool b1 = (v > tv[1]) | ((v == tv[1]) & (j < ti[1]));
        bool b2 = (v > tv[2]) | ((v == tv[2]) & (j < ti[2]));
        if (b0)      { tv[3]=tv[2];ti[3]=ti[2]; tv[2]=tv[1];ti[2]=ti[1]; tv[1]=tv[0];ti[1]=ti[0]; tv[0]=v;ti[0]=j; }
        else if (b1) { tv[3]=tv[2];ti[3]=ti[2]; tv[2]=tv[1];ti[2]=ti[1]; tv[1]=v;ti[1]=j; }
        else if (b2) { tv[3]=tv[2];ti[3]=ti[2]; tv[2]=v;ti[2]=j; }
        else         { tv[3]=v;ti[3]=j; }
    }
}

// ---- K-fill: plain cached grid-stride zero of both outputs ----
__global__ __launch_bounds__(256) void fill_zero(f32x4* __restrict__ o) {
    const f32x4 z = {0.f, 0.f, 0.f, 0.f};
    const size_t total = (size_t)NN * NN / 2;
    const size_t stride = (size_t)2048 * 256;
    size_t idx = (size_t)blockIdx.x * 256 + threadIdx.x;
#pragma unroll 4
    for (; idx < total; idx += stride) o[idx] = z;
}

// ---- K1: normalize rows, emit bf16 x-hat in MFMA-fragment-major layout ----
__global__ __launch_bounds__(256) void norm_frag(const float* __restrict__ x,
                                                 u32x4* __restrict__ F) {
    const int t = threadIdx.x;
    const int c = blockIdx.x;
    const int row = t >> 4;
    const int seg = t & 15;
    const float* xr = x + (size_t)(c * 16 + row) * DD + seg * 8;
    float4 v0 = reinterpret_cast<const float4*>(xr)[0];
    float4 v1 = reinterpret_cast<const float4*>(xr)[1];
    float ss = v0.x*v0.x + v0.y*v0.y + v0.z*v0.z + v0.w*v0.w
             + v1.x*v1.x + v1.y*v1.y + v1.z*v1.z + v1.w*v1.w;
#pragma unroll
    for (int d = 1; d < 16; d <<= 1) ss += __shfl_xor(ss, d);
    const float inv = 1.0f / fmaxf(sqrtf(ss), 1e-12f);
    u32x4 p;
    p.x = ((unsigned)f2bf(v0.y*inv) << 16) | f2bf(v0.x*inv);
    p.y = ((unsigned)f2bf(v0.w*inv) << 16) | f2bf(v0.z*inv);
    p.z = ((unsigned)f2bf(v1.y*inv) << 16) | f2bf(v1.x*inv);
    p.w = ((unsigned)f2bf(v1.w*inv) << 16) | f2bf(v1.z*inv);
    const int kc = seg >> 2, r = seg & 3;
    F[(size_t)(c * 4 + kc) * 64 + r * 16 + row] = p;
}

// ---- K2: branch-free register-histogram select + append + exact rerank ----
__global__ __launch_bounds__(512) void build(const short8* __restrict__ F,
                                             const float* __restrict__ x,
                                             float* __restrict__ adj,
                                             float* __restrict__ ew) {
    __shared__ u64 hsA_lo[16][8], hsA_hi[16][8], hsB_lo[16][8], hsB_hi[16][8];
    __shared__ float rowthr[32];
    __shared__ unsigned cnt[32];
    __shared__ int li[32][CAP];

    const int t = threadIdx.x, lane = t & 63, w = t >> 6;   // 8 waves
    const int i0 = blockIdx.x * 32;
    const int l15 = lane & 15, r = lane >> 4;
    const int g0 = i0 >> 4;

    if (t < 32) cnt[t] = 0u;

    short8 rf0[4], rf1[4];
#pragma unroll
    for (int kc = 0; kc < 4; ++kc) {
        rf0[kc] = F[(size_t)(g0 * 4 + kc) * 64 + lane];
        rf1[kc] = F[(size_t)((g0 + 1) * 4 + kc) * 64 + lane];
    }

    u64 hA = 0ull, hB = 0ull;     // 8 x 8-bit packed bucket counters per row

    // ---- sweep 1: branch-free packed histogram (diagonal included) ----
    for (int cg = w; cg < NG; cg += 8) {
        const short8 a0 = F[(size_t)(cg * 4 + 0) * 64 + lane];
        const short8 a1 = F[(size_t)(cg * 4 + 1) * 64 + lane];
        const short8 a2 = F[(size_t)(cg * 4 + 2) * 64 + lane];
        const short8 a3 = F[(size_t)(cg * 4 + 3) * 64 + lane];
        f32x4 acc0 = {0.f, 0.f, 0.f, 0.f}, acc1 = {0.f, 0.f, 0.f, 0.f};
        acc0 = __builtin_amdgcn_mfma_f32_16x16x32_bf16(a0, rf0[0], acc0, 0, 0, 0);
        acc1 = __builtin_amdgcn_mfma_f32_16x16x32_bf16(a0, rf1[0], acc1, 0, 0, 0);
        acc0 = __builtin_amdgcn_mfma_f32_16x16x32_bf16(a1, rf0[1], acc0, 0, 0, 0);
        acc1 = __builtin_amdgcn_mfma_f32_16x16x32_bf16(a1, rf1[1], acc1, 0, 0, 0);
        acc0 = __builtin_amdgcn_mfma_f32_16x16x32_bf16(a2, rf0[2], acc0, 0, 0, 0);
        acc1 = __builtin_amdgcn_mfma_f32_16x16x32_bf16(a2, rf1[2], acc1, 0, 0, 0);
        acc0 = __builtin_amdgcn_mfma_f32_16x16x32_bf16(a3, rf0[3], acc0, 0, 0, 0);
        acc1 = __builtin_amdgcn_mfma_f32_16x16x32_bf16(a3, rf1[3], acc1, 0, 0, 0);
#pragma unroll
        for (int q = 0; q < 4; ++q) {
            {
                const float v = acc0[q];
                int b = (int)((v - T0) * 40.0f);
                b = b < 0 ? 0 : (b > 7 ? 7 : b);
                hA += (u64)(v > T0) << (b * 8);
            }
            {
                const float v = acc1[q];
                int b = (int)((v - T0) * 40.0f);
                b = b < 0 ? 0 : (b > 7 ? 7 : b);
                hB += (u64)(v > T0) << (b * 8);
            }
        }
    }

    // merge the 4 r-lanes per row (byte headroom: 4 x ~30 << 255)
    hA += shfl_xor_u64(hA, 16); hA += shfl_xor_u64(hA, 32);
    hB += shfl_xor_u64(hB, 16); hB += shfl_xor_u64(hB, 32);
    if (r == 0) {
        const u64 M = 0x00FF00FF00FF00FFull;
        hsA_lo[l15][w] = hA & M;  hsA_hi[l15][w] = (hA >> 8) & M;
        hsB_lo[l15][w] = hB & M;  hsB_hi[l15][w] = (hB >> 8) & M;
    }
    __syncthreads();

    // ---- per-row threshold: highest bucket with cumulative (incl self) >= KSEL ----
    if (t < 32) {
        const int row = t & 15;
        u64 lo = 0ull, hi = 0ull;
        if (t < 16) {
#pragma unroll
            for (int ww = 0; ww < 8; ++ww) { lo += hsA_lo[row][ww]; hi += hsA_hi[row][ww]; }
        } else {
#pragma unroll
            for (int ww = 0; ww < 8; ++ww) { lo += hsB_lo[row][ww]; hi += hsB_hi[row][ww]; }
        }
        unsigned cum = 0; int pick = 0;
#pragma unroll
        for (int b = 7; b >= 0; --b) {
            unsigned c = (unsigned)(((b & 1) ? hi : lo) >> (16 * (b >> 1))) & 0xFFFFu;
            cum += c;
            if (cum >= KSEL) { pick = b; break; }
        }
        rowthr[t] = T0 + BWID * (float)pick - DELTA;
    }
    __syncthreads();
    const float sTa = rowthr[l15], sTb = rowthr[l15 + 16];

    // ---- sweep 2: append candidates above per-row threshold (diag included) ----
    for (int cg = w; cg < NG; cg += 8) {
        const short8 a0 = F[(size_t)(cg * 4 + 0) * 64 + lane];
        const short8 a1 = F[(size_t)(cg * 4 + 1) * 64 + lane];
        const short8 a2 = F[(size_t)(cg * 4 + 2) * 64 + lane];
        const short8 a3 = F[(size_t)(cg * 4 + 3) * 64 + lane];
        f32x4 acc0 = {0.f, 0.f, 0.f, 0.f}, acc1 = {0.f, 0.f, 0.f, 0.f};
        acc0 = __builtin_amdgcn_mfma_f32_16x16x32_bf16(a0, rf0[0], acc0, 0, 0, 0);
        acc1 = __builtin_amdgcn_mfma_f32_16x16x32_bf16(a0, rf1[0], acc1, 0, 0, 0);
        acc0 = __builtin_amdgcn_mfma_f32_16x16x32_bf16(a1, rf0[1], acc0, 0, 0, 0);
        acc1 = __builtin_amdgcn_mfma_f32_16x16x32_bf16(a1, rf1[1], acc1, 0, 0, 0);
        acc0 = __builtin_amdgcn_mfma_f32_16x16x32_bf16(a2, rf0[2], acc0, 0, 0, 0);
        acc1 = __builtin_amdgcn_mfma_f32_16x16x32_bf16(a2, rf1[2], acc1, 0, 0, 0);
        acc0 = __builtin_amdgcn_mfma_f32_16x16x32_bf16(a3, rf0[3], acc0, 0, 0, 0);
        acc1 = __builtin_amdgcn_mfma_f32_16x16x32_bf16(a3, rf1[3], acc1, 0, 0, 0);
        const int jb = cg * 16 + r * 4;
#pragma unroll
        for (int q = 0; q < 4; ++q) {
            const int j = jb + q;
            float v = acc0[q];
            if (v > sTa) {
                unsigned p = atomicAdd(&cnt[l15], 1u);
                if (p < CAP) li[l15][p] = j;
            }
            v = acc1[q];
            if (v > sTb) {
                unsigned p = atomicAdd(&cnt[l15 + 16], 1u);
                if (p < CAP) li[l15 + 16][p] = j;
            }
        }
    }
    __syncthreads();

    // ---- exact fp32 rerank + scatter: wave w handles rows w*4 .. w*4+3 ----
    for (int rr = 0; rr < 4; ++rr) {
        const int lrow = w * 4 + rr;
        const int i = i0 + lrow;
        const int n = min((int)cnt[lrow], CAP);
        const float2 a = reinterpret_cast<const float2*>(x + (size_t)i * DD)[lane];
        float ss = a.x * a.x + a.y * a.y;
#pragma unroll
        for (int d = 1; d < 64; d <<= 1) ss += __shfl_xor(ss, d);
        const float ni = fmaxf(sqrtf(ss), 1e-12f);
        float tv[4]; int ti[4];
#pragma unroll
        for (int s = 0; s < 4; ++s) { tv[s] = -1e30f; ti[s] = 0x7fffffff; }
        for (int c = 0; c < n; ++c) {
            const int j = li[lrow][c];
            if (j == i) continue;                       // skip self (wave-uniform)
            const float2 b = reinterpret_cast<const float2*>(x + (size_t)j * DD)[lane];
            float dp = a.x * b.x + a.y * b.y;
            float sb = b.x * b.x + b.y * b.y;
#pragma unroll
            for (int d = 1; d < 64; d <<= 1) {
                dp += __shfl_xor(dp, d);
                sb += __shfl_xor(sb, d);
            }
            const float sim = dp / (ni * fmaxf(sqrtf(sb), 1e-12f));
            ins4(sim, j, tv, ti);
        }
        if (lane == 0) {
#pragma unroll
            for (int s = 0; s < 4; ++s)
                if (tv[s] > THRESH) {
                    adj[(size_t)i * NN + ti[s]] = 1.0f;
                    ew [(size_t)i * NN + ti[s]] = tv[s];
                }
        }
    }
}

extern "C" void kernel_launch(void* const* d_in, const int* in_sizes, int n_in,
                              void* d_out, int out_size, void* d_ws, size_t ws_size,
                              hipStream_t stream) {
    const float* x = (const float*)d_in[0];
    u32x4* F = (u32x4*)d_ws;                               // 2 MB fragment-major x-hat
    float* adj = (float*)d_out;
    float* ew  = adj + (size_t)NN * NN;

    hipLaunchKernelGGL(fill_zero, dim3(2048),  dim3(256), 0, stream, (f32x4*)d_out);
    hipLaunchKernelGGL(norm_frag, dim3(NG),    dim3(256), 0, stream, x, F);
    hipLaunchKernelGGL(build,     dim3(NN/32), dim3(512), 0, stream,
                       (const short8*)F, x, adj, ew);
}